// Round 1
// baseline (48.578 us; speedup 1.0000x reference)
//
#include <hip/hip_runtime.h>

// DotPredictor: out[e] = dot(h[src[e]], h[dst[e]]), D_FEAT = 64 (f32).
// 16 lanes per edge: lane i loads float4 #i of each 64-float row ->
// fully coalesced 256B row reads; shfl_xor reduce within the 16-lane group.

__global__ void dot_edges_kernel(const float* __restrict__ h,
                                 const int* __restrict__ src,
                                 const int* __restrict__ dst,
                                 float* __restrict__ out,
                                 int n_edges) {
    int gtid = blockIdx.x * blockDim.x + threadIdx.x;
    int edge = gtid >> 4;            // 16 lanes per edge
    int sub  = threadIdx.x & 15;     // which float4 of the row
    if (edge >= n_edges) return;

    int u = src[edge];
    int v = dst[edge];

    const float4* __restrict__ hu =
        reinterpret_cast<const float4*>(h + (size_t)u * 64);
    const float4* __restrict__ hv =
        reinterpret_cast<const float4*>(h + (size_t)v * 64);

    float4 a = hu[sub];
    float4 b = hv[sub];

    float acc = a.x * b.x + a.y * b.y + a.z * b.z + a.w * b.w;

    // Reduce across the 16 lanes of this edge's group.
    acc += __shfl_xor(acc, 1, 16);
    acc += __shfl_xor(acc, 2, 16);
    acc += __shfl_xor(acc, 4, 16);
    acc += __shfl_xor(acc, 8, 16);

    if (sub == 0) out[edge] = acc;
}

extern "C" void kernel_launch(void* const* d_in, const int* in_sizes, int n_in,
                              void* d_out, int out_size, void* d_ws, size_t ws_size,
                              hipStream_t stream) {
    const float* h   = (const float*)d_in[0];
    const int*   src = (const int*)d_in[1];
    const int*   dst = (const int*)d_in[2];
    float*       out = (float*)d_out;

    int n_edges = in_sizes[1];

    const int threads = 256;
    const int edges_per_block = threads / 16;  // 16
    int blocks = (n_edges + edges_per_block - 1) / edges_per_block;

    dot_edges_kernel<<<blocks, threads, 0, stream>>>(h, src, dst, out, n_edges);
}

// Round 2
// 34.208 us; speedup vs baseline: 1.4201x; 1.4201x over previous
//
#include <hip/hip_runtime.h>
#include <stdint.h>

// DotPredictor: out[e] = dot(h[src[e]], h[dst[e]]), D_FEAT = 64.
// Strategy: per-launch quantize h to bf16 in d_ws (halves gather bytes,
// doubles effective L2 coverage of the table), then gather with
// 8 lanes/edge x 16B (8 bf16) and shfl-reduce.

__device__ __forceinline__ float bf16w_dot(uint32_t wa, uint32_t wb, float acc) {
    float alo = __uint_as_float(wa << 16);
    float ahi = __uint_as_float(wa & 0xffff0000u);
    float blo = __uint_as_float(wb << 16);
    float bhi = __uint_as_float(wb & 0xffff0000u);
    acc = fmaf(alo, blo, acc);
    acc = fmaf(ahi, bhi, acc);
    return acc;
}

__device__ __forceinline__ uint16_t f32_to_bf16_rne(float f) {
    uint32_t u = __float_as_uint(f);
    u += 0x7fffu + ((u >> 16) & 1u);   // round to nearest even
    return (uint16_t)(u >> 16);
}

// Pack h (f32, n_words*2 elems) -> hb (2x bf16 per uint32 word).
__global__ void convert_h_bf16(const float* __restrict__ h,
                               uint32_t* __restrict__ hb, int n_words) {
    int i = blockIdx.x * blockDim.x + threadIdx.x;
    int stride = gridDim.x * blockDim.x;
    for (; i < n_words; i += stride) {
        float2 f = reinterpret_cast<const float2*>(h)[i];
        uint32_t lo = f32_to_bf16_rne(f.x);
        uint32_t hi = f32_to_bf16_rne(f.y);
        hb[i] = lo | (hi << 16);
    }
}

// 8 lanes per edge; lane i loads uint4 #i (8 bf16) of each 128B row.
__global__ void dot_edges_bf16(const uint32_t* __restrict__ hb,
                               const int* __restrict__ src,
                               const int* __restrict__ dst,
                               float* __restrict__ out,
                               int n_edges) {
    int gtid = blockIdx.x * blockDim.x + threadIdx.x;
    int edge = gtid >> 3;
    int sub  = threadIdx.x & 7;
    if (edge >= n_edges) return;

    int u = src[edge];
    int v = dst[edge];

    const uint4* __restrict__ hu =
        reinterpret_cast<const uint4*>(hb + (size_t)u * 32);
    const uint4* __restrict__ hv =
        reinterpret_cast<const uint4*>(hb + (size_t)v * 32);

    uint4 a = hu[sub];
    uint4 b = hv[sub];

    float acc = 0.f;
    acc = bf16w_dot(a.x, b.x, acc);
    acc = bf16w_dot(a.y, b.y, acc);
    acc = bf16w_dot(a.z, b.z, acc);
    acc = bf16w_dot(a.w, b.w, acc);

    acc += __shfl_xor(acc, 1, 8);
    acc += __shfl_xor(acc, 2, 8);
    acc += __shfl_xor(acc, 4, 8);

    if (sub == 0) out[edge] = acc;
}

// Fallback (f32 path, 16 lanes/edge) if workspace is too small.
__global__ void dot_edges_f32(const float* __restrict__ h,
                              const int* __restrict__ src,
                              const int* __restrict__ dst,
                              float* __restrict__ out,
                              int n_edges) {
    int gtid = blockIdx.x * blockDim.x + threadIdx.x;
    int edge = gtid >> 4;
    int sub  = threadIdx.x & 15;
    if (edge >= n_edges) return;

    int u = src[edge];
    int v = dst[edge];
    const float4* hu = reinterpret_cast<const float4*>(h + (size_t)u * 64);
    const float4* hv = reinterpret_cast<const float4*>(h + (size_t)v * 64);
    float4 a = hu[sub];
    float4 b = hv[sub];
    float acc = a.x * b.x + a.y * b.y + a.z * b.z + a.w * b.w;
    acc += __shfl_xor(acc, 1, 16);
    acc += __shfl_xor(acc, 2, 16);
    acc += __shfl_xor(acc, 4, 16);
    acc += __shfl_xor(acc, 8, 16);
    if (sub == 0) out[edge] = acc;
}

extern "C" void kernel_launch(void* const* d_in, const int* in_sizes, int n_in,
                              void* d_out, int out_size, void* d_ws, size_t ws_size,
                              hipStream_t stream) {
    const float* h   = (const float*)d_in[0];
    const int*   src = (const int*)d_in[1];
    const int*   dst = (const int*)d_in[2];
    float*       out = (float*)d_out;

    int n_edges = in_sizes[1];
    int n_feat_elems = in_sizes[0];          // 50000 * 64
    int n_words = n_feat_elems / 2;          // 2 bf16 per uint32
    size_t need = (size_t)n_words * 4;

    if (ws_size >= need) {
        uint32_t* hb = (uint32_t*)d_ws;

        int cthreads = 256;
        int cblocks = (n_words + cthreads - 1) / cthreads;
        if (cblocks > 2048) cblocks = 2048;
        convert_h_bf16<<<cblocks, cthreads, 0, stream>>>(h, hb, n_words);

        const int threads = 256;
        const int epb = threads / 8;         // 32 edges per block
        int blocks = (n_edges + epb - 1) / epb;
        dot_edges_bf16<<<blocks, threads, 0, stream>>>(hb, src, dst, out, n_edges);
    } else {
        const int threads = 256;
        const int epb = threads / 16;
        int blocks = (n_edges + epb - 1) / epb;
        dot_edges_f32<<<blocks, threads, 0, stream>>>(h, src, dst, out, n_edges);
    }
}

// Round 3
// 33.246 us; speedup vs baseline: 1.4612x; 1.0289x over previous
//
#include <hip/hip_runtime.h>
#include <stdint.h>

// DotPredictor: out[e] = dot(h[src[e]], h[dst[e]]), D_FEAT = 64.
// v3: bf16 table in d_ws (halves gather bytes) +
//     2 edges per 8-lane group (4 in-flight gathers/thread, 2x MLP) +
//     non-temporal index loads / output stores (keep L2 for the table).

__device__ __forceinline__ float bf16w_dot(uint32_t wa, uint32_t wb, float acc) {
    float alo = __uint_as_float(wa << 16);
    float ahi = __uint_as_float(wa & 0xffff0000u);
    float blo = __uint_as_float(wb << 16);
    float bhi = __uint_as_float(wb & 0xffff0000u);
    acc = fmaf(alo, blo, acc);
    acc = fmaf(ahi, bhi, acc);
    return acc;
}

__device__ __forceinline__ float dot4w(uint4 a, uint4 b) {
    float acc = 0.f;
    acc = bf16w_dot(a.x, b.x, acc);
    acc = bf16w_dot(a.y, b.y, acc);
    acc = bf16w_dot(a.z, b.z, acc);
    acc = bf16w_dot(a.w, b.w, acc);
    return acc;
}

__device__ __forceinline__ uint16_t f32_to_bf16_rne(float f) {
    uint32_t u = __float_as_uint(f);
    u += 0x7fffu + ((u >> 16) & 1u);   // round to nearest even
    return (uint16_t)(u >> 16);
}

// Pack h (f32, n_words*2 elems) -> hb (2x bf16 per uint32 word).
__global__ void convert_h_bf16(const float* __restrict__ h,
                               uint32_t* __restrict__ hb, int n_words) {
    int i = blockIdx.x * blockDim.x + threadIdx.x;
    int stride = gridDim.x * blockDim.x;
    for (; i < n_words; i += stride) {
        float2 f = reinterpret_cast<const float2*>(h)[i];
        uint32_t lo = f32_to_bf16_rne(f.x);
        uint32_t hi = f32_to_bf16_rne(f.y);
        hb[i] = lo | (hi << 16);
    }
}

// 8 lanes per edge-group; each group handles 2 consecutive edges.
// Lane sub loads uint4 #sub (8 bf16 = 16B) of each 128B row.
__global__ void dot_edges_bf16_x2(const uint32_t* __restrict__ hb,
                                  const int* __restrict__ src,
                                  const int* __restrict__ dst,
                                  float* __restrict__ out,
                                  int n_edges) {
    int gtid = blockIdx.x * blockDim.x + threadIdx.x;
    int group = gtid >> 3;
    int sub   = threadIdx.x & 7;
    int e0 = group * 2;
    if (e0 >= n_edges) return;
    int e1 = e0 + 1;
    bool has1 = (e1 < n_edges);

    // Streaming data: non-temporal so it doesn't evict table rows from L2.
    int u0 = __builtin_nontemporal_load(&src[e0]);
    int v0 = __builtin_nontemporal_load(&dst[e0]);
    int u1 = has1 ? __builtin_nontemporal_load(&src[e1]) : u0;
    int v1 = has1 ? __builtin_nontemporal_load(&dst[e1]) : v0;

    const uint4* __restrict__ hu0 =
        reinterpret_cast<const uint4*>(hb + (size_t)u0 * 32);
    const uint4* __restrict__ hv0 =
        reinterpret_cast<const uint4*>(hb + (size_t)v0 * 32);
    const uint4* __restrict__ hu1 =
        reinterpret_cast<const uint4*>(hb + (size_t)u1 * 32);
    const uint4* __restrict__ hv1 =
        reinterpret_cast<const uint4*>(hb + (size_t)v1 * 32);

    // 4 independent gathers in flight per thread.
    uint4 a0 = hu0[sub];
    uint4 b0 = hv0[sub];
    uint4 a1 = hu1[sub];
    uint4 b1 = hv1[sub];

    float acc0 = dot4w(a0, b0);
    float acc1 = dot4w(a1, b1);

    acc0 += __shfl_xor(acc0, 1, 8);
    acc1 += __shfl_xor(acc1, 1, 8);
    acc0 += __shfl_xor(acc0, 2, 8);
    acc1 += __shfl_xor(acc1, 2, 8);
    acc0 += __shfl_xor(acc0, 4, 8);
    acc1 += __shfl_xor(acc1, 4, 8);

    if (sub == 0) {
        __builtin_nontemporal_store(acc0, &out[e0]);
        if (has1) __builtin_nontemporal_store(acc1, &out[e1]);
    }
}

// Fallback (f32 path, 16 lanes/edge) if workspace is too small.
__global__ void dot_edges_f32(const float* __restrict__ h,
                              const int* __restrict__ src,
                              const int* __restrict__ dst,
                              float* __restrict__ out,
                              int n_edges) {
    int gtid = blockIdx.x * blockDim.x + threadIdx.x;
    int edge = gtid >> 4;
    int sub  = threadIdx.x & 15;
    if (edge >= n_edges) return;

    int u = src[edge];
    int v = dst[edge];
    const float4* hu = reinterpret_cast<const float4*>(h + (size_t)u * 64);
    const float4* hv = reinterpret_cast<const float4*>(h + (size_t)v * 64);
    float4 a = hu[sub];
    float4 b = hv[sub];
    float acc = a.x * b.x + a.y * b.y + a.z * b.z + a.w * b.w;
    acc += __shfl_xor(acc, 1, 16);
    acc += __shfl_xor(acc, 2, 16);
    acc += __shfl_xor(acc, 4, 16);
    acc += __shfl_xor(acc, 8, 16);
    if (sub == 0) out[edge] = acc;
}

extern "C" void kernel_launch(void* const* d_in, const int* in_sizes, int n_in,
                              void* d_out, int out_size, void* d_ws, size_t ws_size,
                              hipStream_t stream) {
    const float* h   = (const float*)d_in[0];
    const int*   src = (const int*)d_in[1];
    const int*   dst = (const int*)d_in[2];
    float*       out = (float*)d_out;

    int n_edges = in_sizes[1];
    int n_feat_elems = in_sizes[0];          // 50000 * 64
    int n_words = n_feat_elems / 2;          // 2 bf16 per uint32
    size_t need = (size_t)n_words * 4;

    if (ws_size >= need) {
        uint32_t* hb = (uint32_t*)d_ws;

        int cthreads = 256;
        int cblocks = (n_words + cthreads - 1) / cthreads;
        if (cblocks > 2048) cblocks = 2048;
        convert_h_bf16<<<cblocks, cthreads, 0, stream>>>(h, hb, n_words);

        const int threads = 256;
        // 8 lanes/group, 2 edges/group -> 64 edges per 256-thread block
        int n_groups = (n_edges + 1) / 2;
        int blocks = (n_groups * 8 + threads - 1) / threads;
        dot_edges_bf16_x2<<<blocks, threads, 0, stream>>>(hb, src, dst, out, n_edges);
    } else {
        const int threads = 256;
        const int epb = threads / 16;
        int blocks = (n_edges + epb - 1) / epb;
        dot_edges_f32<<<blocks, threads, 0, stream>>>(h, src, dst, out, n_edges);
    }
}